// Round 7
// baseline (557.733 us; speedup 1.0000x reference)
//
#include <hip/hip_runtime.h>

// ChebyKANLayer: y[t,o] = bias[o] + sum_k A[t,k]*B[k,o], K=8192, k=i*8+(d-1), d=1..8.
// R13: K-SPLIT gemm — grid 512 = (256 output tiles) x (2 K-halves), 2 blocks/CU,
// 4 waves/SIMD (R12 post-mortem: 30% dead time from 2-wave/SIMD phase serialization).
// Inner K-step byte-identical to verified R12 (gen-A-in-reg + B/seed LDS ring).
// Halves write f32 partials; combine pass adds part0+part1+bias. Prep split into
// prep_B / prep_th kernels so rocprof finally attributes the persistent ~90us.

typedef __bf16 bf16;
typedef __bf16 bf16x8 __attribute__((ext_vector_type(8)));
typedef float f32x2 __attribute__((ext_vector_type(2)));
typedef float f32x4 __attribute__((ext_vector_type(4)));
typedef float f32x16 __attribute__((ext_vector_type(16)));

#define MFMA __builtin_amdgcn_mfma_f32_32x32x16_bf16

__device__ __forceinline__ void g2lds16(const void* g, void* l) {
  __builtin_amdgcn_global_load_lds(
      (const __attribute__((address_space(1))) unsigned int*)g,
      (__attribute__((address_space(3))) unsigned int*)l, 16, 0, 0);
}

__device__ __forceinline__ float fast_tanh(float a) {
  float e = __expf(a + a);
  return 1.f - 2.f * __builtin_amdgcn_rcpf(e + 1.f);   // saturating, NaN-free
}

// ============================ PREP A: B repack + bias partials ============================
// B global layout (verified): [nb 0..7][kt 0..127][8192 bf16], elem
//   (((ks*4+n32)*2+h)*32+o31)*8 + (d-1), i = kt*8 + 2ks + h.
// bias_p[p][o] = sum_{i in 32-block p} C[i][o][0].
__global__ __launch_bounds__(256)
void cheby_prepB(const float* __restrict__ C, bf16* __restrict__ B,
                 float* __restrict__ bias_p) {
  const int b2 = blockIdx.x, tid = threadIdx.x;
  __shared__ float tile[32][292];
  const int i0 = (b2 >> 5) * 32, o0 = (b2 & 31) * 32;
  {
    const int r = tid >> 3, seg = tid & 7;
    const float* src = C + (size_t)(i0 + r) * 9216 + (size_t)o0 * 9 + seg * 36;
    float* dst = &tile[r][seg * 36];
    #pragma unroll
    for (int v = 0; v < 9; ++v) *(f32x4*)(dst + v * 4) = *(const f32x4*)(src + v * 4);
  }
  __syncthreads();
  #pragma unroll
  for (int j = 0; j < 4; ++j) {
    int e = tid + 256 * j;
    int il = e >> 5, ol = e & 31;
    int i = i0 + il, o = o0 + ol;
    bf16x8 v;
    #pragma unroll
    for (int d = 0; d < 8; ++d) v[d] = (bf16)tile[il][ol * 9 + 1 + d];
    const int cc = i & 7;
    size_t tnum = (size_t)(o >> 7) * 128 + (i >> 3);
    const int widx = (((cc >> 1) * 4 + ((o & 127) >> 5)) * 2 + (cc & 1)) * 32 + (o & 31);
    *(bf16x8*)(B + tnum * 8192 + widx * 8) = v;
  }
  if (tid < 32) {
    float s = 0.f;
    #pragma unroll
    for (int i = 0; i < 32; ++i) s += tile[i][tid * 9];
    bias_p[(size_t)(b2 >> 5) * 1024 + o0 + tid] = s;
  }
}

// ============================ PREP B: th2 (pos-major tanh) + bias reduce ============================
// th2[32][128][8][256]: th2[mb][kt][pos][row] = tanh(x[mb*256+row][kt*8+li]),
//   li = (pos>>2) + 2*(pos&3)  (verified R12 layout).
// bids [1024,1028): bias[o] = sum_p bias_p[p][o] (bias_p from prior prepB launch).
__global__ __launch_bounds__(256)
void cheby_prepT(const float* __restrict__ x, const float* __restrict__ bias_p,
                 float* __restrict__ th2, float* __restrict__ bias) {
  const int bid = blockIdx.x, tid = threadIdx.x;
  if (bid >= 1024) {                                 // ---- bias reduce (4 blocks)
    const int col = (bid - 1024) * 256 + tid;
    float s = 0.f;
    #pragma unroll
    for (int p = 0; p < 32; ++p) s += bias_p[(size_t)p * 1024 + col];
    bias[col] = s;
    return;
  }
  __shared__ float xs[64][129];                      // pad: LDS reads 2-way (free)
  const int r0 = (bid >> 3) * 64, c0 = (bid & 7) * 128;
  #pragma unroll
  for (int it = 0; it < 8; ++it) {                   // coalesced x stage: 64x128 f32
    const int e = tid + it * 256;
    const int rr = e >> 5, c4 = (e & 31) * 4;
    f32x4 v = *(const f32x4*)(x + (size_t)(r0 + rr) * 1024 + c0 + c4);
    xs[rr][c4 + 0] = v.x; xs[rr][c4 + 1] = v.y;
    xs[rr][c4 + 2] = v.z; xs[rr][c4 + 3] = v.w;
  }
  __syncthreads();
  const int row = tid & 63, kq = tid >> 6;
  const int mb = r0 >> 8, rowp = (r0 & 255) + row;
  const int kt0 = c0 >> 3;
  float* outp = th2 + (size_t)mb * 128 * 2048;
  #pragma unroll
  for (int kk = 0; kk < 4; ++kk) {
    const int kt = kq * 4 + kk;
    #pragma unroll
    for (int li = 0; li < 8; ++li) {
      float z = fast_tanh(xs[row][kt * 8 + li]);
      const int pos = (li & 1) * 4 + (li >> 1);
      outp[((size_t)(kt0 + kt) * 8 + pos) * 256 + rowp] = z;
    }
  }
}

// ============================ GEMM (K-split, verified R12 inner step) ============================
// Grid 512 = 256 tiles x 2 K-halves; 512 thr, 8 waves (4M x 2N), wave 64x64, 64 K-steps.
// Ring[3] x 24KB: [0,8192) bf16 B image, [8192,12288) seeds (2048 f32 pos-major).
// Pairing: wgid = (bid&7)*64 + (bid>>3); tile = wgid>>1, kh = wgid&1 -> the two
// halves of a tile sit 8 bids apart = same XCD (B/th2 L2 reuse).
__global__ __launch_bounds__(512, 4)
void cheby_gemm8(const float* __restrict__ th2, const bf16* __restrict__ B,
                 float* __restrict__ part) {
  __shared__ bf16 ring[3][12288];                    // 3 x 24 KB = 72 KB -> 2 blocks/CU
  const int tid = threadIdx.x;
  const int lane = tid & 63, w = tid >> 6;
  const int wm = w >> 1, wn = w & 1;
  const int bid = blockIdx.x;
  const int wgid = (bid & 7) * 64 + (bid >> 3);      // bijective (512 = 8*64)
  const int tile = wgid >> 1, kh = wgid & 1;
  const int mb2 = tile >> 3, nb = tile & 7;

  const int ml = lane & 31, h = lane >> 5;
  const int bBase = wn * 1024 + h * 256 + ml * 8;    // + ks*2048, + nt*512
  const int row0 = wm * 64;
  const int sOff = h * 1024 + row0 + ml;             // f32: (h*4+ks)*256 + row; +32 row1

  const bf16*  bG = B   + (size_t)nb * 1048576 + (size_t)kh * 524288 + tid * 8;
  const float* tG = th2 + (size_t)mb2 * 262144 + (size_t)kh * 131072 + tid * 4;

  f32x16 acc[2][2];
  #pragma unroll
  for (int a = 0; a < 2; ++a)
    #pragma unroll
    for (int b = 0; b < 2; ++b)
      #pragma unroll
      for (int r = 0; r < 16; ++r) acc[a][b][r] = 0.f;

  auto issue3 = [&](int t, int p) {
    g2lds16(bG + (size_t)t * 8192,        &ring[p][tid * 8]);
    g2lds16(bG + (size_t)t * 8192 + 4096, &ring[p][4096 + tid * 8]);
    g2lds16(tG + (size_t)t * 2048,        &ring[p][8192 + tid * 8]);
  };

  issue3(0, 0); issue3(1, 1);
  asm volatile("s_waitcnt vmcnt(3)" ::: "memory");
  __builtin_amdgcn_s_barrier();

  auto step = [&](int t, int pC, int pN) {
    if (t + 2 < 64) issue3(t + 2, pN);
    const bf16* ra = &ring[pC][0];
    const float* seedL = (const float*)(ra + 8192);
    bf16x8 bfr[2][4], afr[2][4];
    #pragma unroll
    for (int ks = 0; ks < 4; ++ks) {
      bfr[0][ks] = *(const bf16x8*)(ra + bBase + ks * 2048);
      bfr[1][ks] = *(const bf16x8*)(ra + bBase + ks * 2048 + 512);
    }
    #pragma unroll
    for (int ks = 0; ks < 4; ++ks) {                 // verified Chebyshev chain
      f32x2 tv = { seedL[sOff + ks * 256], seedL[sOff + ks * 256 + 32] };
      f32x2 t2 = tv + tv;
      f32x2 prev = {1.f, 1.f}, cur = tv;
      #pragma unroll
      for (int j = 0; j < 8; ++j) {
        afr[0][ks][j] = (bf16)cur.x;
        afr[1][ks][j] = (bf16)cur.y;
        f32x2 nx = t2 * cur - prev;
        prev = cur; cur = nx;
      }
    }
    __builtin_amdgcn_s_setprio(1);
    #pragma unroll
    for (int ks = 0; ks < 4; ++ks) {
      acc[0][0] = MFMA(afr[0][ks], bfr[0][ks], acc[0][0], 0, 0, 0);
      acc[0][1] = MFMA(afr[0][ks], bfr[1][ks], acc[0][1], 0, 0, 0);
      acc[1][0] = MFMA(afr[1][ks], bfr[0][ks], acc[1][0], 0, 0, 0);
      acc[1][1] = MFMA(afr[1][ks], bfr[1][ks], acc[1][1], 0, 0, 0);
    }
    __builtin_amdgcn_s_setprio(0);
    asm volatile("s_waitcnt lgkmcnt(0)" ::: "memory");
    if (t <= 61) asm volatile("s_waitcnt vmcnt(3)" ::: "memory");  // batch(t+1) landed
    else         asm volatile("s_waitcnt vmcnt(0)" ::: "memory");
    __builtin_amdgcn_s_barrier();
  };

  #pragma unroll 1
  for (int t3 = 0; t3 < 63; t3 += 3) {               // steps 0..62
    step(t3,     0, 2);
    step(t3 + 1, 1, 0);
    step(t3 + 2, 2, 1);
  }
  step(63, 0, 2);                                    // 63%3 == 0; no issue

  // epilogue -> partials (bias added in combine). C/D: col=lane&31, row=(r&3)+8*(r>>2)+4*h
  const int c0 = nb * 128 + wn * 64 + ml;
  const int r0 = mb2 * 256 + wm * 64;
  float* pb = part + (size_t)kh * 8388608;
  #pragma unroll
  for (int mt = 0; mt < 2; ++mt)
    #pragma unroll
    for (int r = 0; r < 16; ++r) {
      int row = r0 + mt * 32 + (r & 3) + 8 * (r >> 2) + 4 * h;
      float* po = pb + (size_t)row * 1024 + c0;
      po[0]  = acc[mt][0][r];
      po[32] = acc[mt][1][r];
    }
}

// ============================ COMBINE ============================
__global__ __launch_bounds__(256)
void cheby_combine(const float* __restrict__ part, const float* __restrict__ bias,
                   float* __restrict__ out) {
  const size_t e = ((size_t)blockIdx.x * 256 + threadIdx.x) * 4;
  f32x4 p0 = *(const f32x4*)(part + e);
  f32x4 p1 = *(const f32x4*)(part + 8388608 + e);
  f32x4 b  = *(const f32x4*)(bias + (e & 1023));
  f32x4 r  = p0 + p1 + b;
  *(f32x4*)(out + e) = r;
}

// ---- naive fallback (ws too small) — correct, slow, should never run
__global__ __launch_bounds__(256)
void cheby_naive(const float* __restrict__ x, const float* __restrict__ C,
                 float* __restrict__ out) {
  const int t = blockIdx.x, tid = threadIdx.x;
  float acc[4] = {0.f, 0.f, 0.f, 0.f};
  for (int i = 0; i < 1024; ++i) {
    float th = tanhf(x[(size_t)t * 1024 + i]);
    float T[9]; T[0] = 1.f; T[1] = th;
    #pragma unroll
    for (int d = 2; d < 9; ++d) T[d] = 2.f * th * T[d - 1] - T[d - 2];
    #pragma unroll
    for (int j = 0; j < 4; ++j) {
      const float* cp = &C[((size_t)i * 1024 + tid + j * 256) * 9];
      float s = 0.f;
      #pragma unroll
      for (int d = 0; d < 9; ++d) s += T[d] * cp[d];
      acc[j] += s;
    }
  }
  #pragma unroll
  for (int j = 0; j < 4; ++j) out[(size_t)t * 1024 + tid + j * 256] = acc[j];
}

extern "C" void kernel_launch(void* const* d_in, const int* in_sizes, int n_in,
                              void* d_out, int out_size, void* d_ws, size_t ws_size,
                              hipStream_t stream) {
  (void)in_sizes; (void)n_in; (void)out_size;
  const float* x = (const float*)d_in[0];
  const float* C = (const float*)d_in[1];
  float* out = (float*)d_out;

  const size_t b_bytes    = (size_t)8 * 128 * 8192 * 2;     // 16.78 MB
  const size_t bp_bytes   = (size_t)32 * 1024 * 4;          // 128 KB
  const size_t bias_bytes = (size_t)1024 * 4 + 3072;        // 4 KB (+ pad to 4 KB align)
  const size_t th_bytes   = (size_t)32 * 128 * 8 * 256 * 4; // 33.55 MB
  const size_t part_bytes = (size_t)2 * 8192 * 1024 * 4;    // 67.11 MB

  if (ws_size >= b_bytes + bp_bytes + bias_bytes + th_bytes + part_bytes) {
    char* p = (char*)d_ws;
    bf16*  B      = (bf16*)p;                          p += b_bytes;
    float* bias_p = (float*)p;                         p += bp_bytes;
    float* bias   = (float*)p;                         p += bias_bytes;
    float* th2    = (float*)p;                         p += th_bytes;
    float* part   = (float*)p;
    cheby_prepB<<<1024, 256, 0, stream>>>(C, B, bias_p);
    cheby_prepT<<<1028, 256, 0, stream>>>(x, bias_p, th2, bias);
    cheby_gemm8<<<512, 512, 0, stream>>>(th2, B, part);
    cheby_combine<<<8192, 256, 0, stream>>>(part, bias, out);
  } else {
    cheby_naive<<<8192, 256, 0, stream>>>(x, C, out);
  }
}

// Round 8
// 255.417 us; speedup vs baseline: 2.1836x; 2.1836x over previous
//
#include <hip/hip_runtime.h>

// ChebyKANLayer: y[t,o] = bias[o] + sum_k A[t,k]*B[k,o], K=8192, k=i*8+(d-1), d=1..8.
// R14: revert R13's fatal launch_bounds(512,4) spill (VGPR capped 128 < 152 needed ->
// 1.4GB scratch churn). Keep R12's verified inner step; de-correlate barrier stalls
// by splitting into 128x128 blocks (256 thr, 4 waves) with 2 INDEPENDENT blocks/CU.
// th2 relaid out per-128-row-block so seeds remain one contiguous g2lds per step.
// No K-split, no partials/combine. Prep split kept for rocprof attribution.

typedef __bf16 bf16;
typedef __bf16 bf16x8 __attribute__((ext_vector_type(8)));
typedef float f32x2 __attribute__((ext_vector_type(2)));
typedef float f32x4 __attribute__((ext_vector_type(4)));
typedef float f32x16 __attribute__((ext_vector_type(16)));

#define MFMA __builtin_amdgcn_mfma_f32_32x32x16_bf16

__device__ __forceinline__ void g2lds16(const void* g, void* l) {
  __builtin_amdgcn_global_load_lds(
      (const __attribute__((address_space(1))) unsigned int*)g,
      (__attribute__((address_space(3))) unsigned int*)l, 16, 0, 0);
}

__device__ __forceinline__ float fast_tanh(float a) {
  float e = __expf(a + a);
  return 1.f - 2.f * __builtin_amdgcn_rcpf(e + 1.f);   // saturating, NaN-free
}

// ============================ PREP A: B repack + bias partials (verified) ============================
// B: [nb 0..7][kt 0..127][8192 bf16], elem (((ks*4+n32)*2+h)*32+o31)*8 + (d-1),
//   i = kt*8 + 2ks + h.  bias_p[p][o] = sum_{i in 32-block p} C[i][o][0].
__global__ __launch_bounds__(256)
void cheby_prepB(const float* __restrict__ C, bf16* __restrict__ B,
                 float* __restrict__ bias_p) {
  const int b2 = blockIdx.x, tid = threadIdx.x;
  __shared__ float tile[32][292];
  const int i0 = (b2 >> 5) * 32, o0 = (b2 & 31) * 32;
  {
    const int r = tid >> 3, seg = tid & 7;
    const float* src = C + (size_t)(i0 + r) * 9216 + (size_t)o0 * 9 + seg * 36;
    float* dst = &tile[r][seg * 36];
    #pragma unroll
    for (int v = 0; v < 9; ++v) *(f32x4*)(dst + v * 4) = *(const f32x4*)(src + v * 4);
  }
  __syncthreads();
  #pragma unroll
  for (int j = 0; j < 4; ++j) {
    int e = tid + 256 * j;
    int il = e >> 5, ol = e & 31;
    int i = i0 + il, o = o0 + ol;
    bf16x8 v;
    #pragma unroll
    for (int d = 0; d < 8; ++d) v[d] = (bf16)tile[il][ol * 9 + 1 + d];
    const int cc = i & 7;
    size_t tnum = (size_t)(o >> 7) * 128 + (i >> 3);
    const int widx = (((cc >> 1) * 4 + ((o & 127) >> 5)) * 2 + (cc & 1)) * 32 + (o & 31);
    *(bf16x8*)(B + tnum * 8192 + widx * 8) = v;
  }
  if (tid < 32) {
    float s = 0.f;
    #pragma unroll
    for (int i = 0; i < 32; ++i) s += tile[i][tid * 9];
    bias_p[(size_t)(b2 >> 5) * 1024 + o0 + tid] = s;
  }
}

// ============================ PREP B: th2 pos-major, 128-row blocks ============================
// th2[mt 0..63][kt 0..127][pos 0..7][row 0..127]: th2[...] = tanh(x[mt*128+row][kt*8+li]),
//   li = (pos>>2) + 2*(pos&3)   (i.e. pos = h*4+ks for i = kt*8 + 2ks + h).
__global__ __launch_bounds__(256)
void cheby_prepT(const float* __restrict__ x, float* __restrict__ th2) {
  const int bid = blockIdx.x, tid = threadIdx.x;
  __shared__ float xs[64][129];                      // pad: LDS reads 2-way (free)
  const int r0 = (bid >> 3) * 64, c0 = (bid & 7) * 128;
  #pragma unroll
  for (int it = 0; it < 8; ++it) {                   // coalesced x stage: 64x128 f32
    const int e = tid + it * 256;
    const int rr = e >> 5, c4 = (e & 31) * 4;
    f32x4 v = *(const f32x4*)(x + (size_t)(r0 + rr) * 1024 + c0 + c4);
    xs[rr][c4 + 0] = v.x; xs[rr][c4 + 1] = v.y;
    xs[rr][c4 + 2] = v.z; xs[rr][c4 + 3] = v.w;
  }
  __syncthreads();
  const int row = tid & 63, kq = tid >> 6;           // wave kq owns 4 local kt
  const int mt = r0 >> 7, rowp = (r0 & 127) + row;   // row within 128-block
  const int kt0 = c0 >> 3;
  float* outp = th2 + (size_t)mt * 131072;           // 128 kt * 1024 f32
  #pragma unroll
  for (int kk = 0; kk < 4; ++kk) {
    const int kt = kq * 4 + kk;
    #pragma unroll
    for (int li = 0; li < 8; ++li) {
      float z = fast_tanh(xs[row][kt * 8 + li]);
      const int pos = (li & 1) * 4 + (li >> 1);
      outp[(size_t)(kt0 + kt) * 1024 + pos * 128 + rowp] = z;  // 256B/wave contiguous
    }
  }
}

// ============================ GEMM (R12 inner step, 128x128 blocks, 2/CU) ============================
// Block 128x128, 256 thr, 4 waves (2M x 2N), wave 64x64, BK=64, 128 K-steps.
// Ring[3] x 20KB: [0,8192) B image (bf16), [8192,10240) seeds (1024 f32 pos-major).
// 5 g2lds/step (B x4 + seeds x1), prefetch distance 2, counted vmcnt(5), one barrier/step.
__global__ __launch_bounds__(256, 2)
void cheby_gemm9(const float* __restrict__ th2, const bf16* __restrict__ B,
                 const float* __restrict__ bias_p, float* __restrict__ out) {
  __shared__ bf16 ring[3][10240];                    // 3 x 20 KB = 60 KB -> 2 blocks/CU
  const int tid = threadIdx.x;
  const int lane = tid & 63, w = tid >> 6;
  const int wm = w >> 1, wn = w & 1;
  const int bid = blockIdx.x;
  const int wgid = (bid & 7) * 64 + (bid >> 3);      // XCD-chunked, bijective (512 = 8*64)
  const int mt = wgid >> 3, nb = wgid & 7;           // rows [mt*128,+128), cols [nb*128,+128)

  const int ml = lane & 31, h = lane >> 5;
  const int bBase = wn * 1024 + h * 256 + ml * 8;    // + ks*2048, + nt*512
  const int sBase = h * 512 + wm * 64 + ml;          // f32: (h*4+ks)*128 + row; +ks*128; +32

  const bf16*  bG = B   + (size_t)nb * 1048576 + tid * 8;
  const float* tG = th2 + (size_t)mt * 131072 + tid * 4;

  f32x16 acc[2][2];
  #pragma unroll
  for (int a = 0; a < 2; ++a)
    #pragma unroll
    for (int b = 0; b < 2; ++b)
      #pragma unroll
      for (int r = 0; r < 16; ++r) acc[a][b][r] = 0.f;

  auto issue5 = [&](int t, int p) {
    #pragma unroll
    for (int c = 0; c < 4; ++c)
      g2lds16(bG + (size_t)t * 8192 + c * 2048, &ring[p][c * 2048 + tid * 8]);
    g2lds16(tG + (size_t)t * 1024, &ring[p][8192 + tid * 8]);   // 4KB seeds
  };

  issue5(0, 0); issue5(1, 1);
  asm volatile("s_waitcnt vmcnt(5)" ::: "memory");
  __builtin_amdgcn_s_barrier();

  auto step = [&](int t, int pC, int pN) {
    if (t + 2 < 128) issue5(t + 2, pN);              // pN=(t+2)%3: dead since end of t-1
    const bf16* ra = &ring[pC][0];
    const float* seedL = (const float*)(ra + 8192);
    bf16x8 bfr[2][4], afr[2][4];                     // step-local (R12 spill-safe form)
    #pragma unroll
    for (int ks = 0; ks < 4; ++ks) {
      bfr[0][ks] = *(const bf16x8*)(ra + bBase + ks * 2048);
      bfr[1][ks] = *(const bf16x8*)(ra + bBase + ks * 2048 + 512);
    }
    #pragma unroll
    for (int ks = 0; ks < 4; ++ks) {                 // verified Chebyshev chain
      f32x2 tv = { seedL[sBase + ks * 128], seedL[sBase + ks * 128 + 32] };
      f32x2 t2 = tv + tv;
      f32x2 prev = {1.f, 1.f}, cur = tv;
      #pragma unroll
      for (int j = 0; j < 8; ++j) {
        afr[0][ks][j] = (bf16)cur.x;
        afr[1][ks][j] = (bf16)cur.y;
        f32x2 nx = t2 * cur - prev;
        prev = cur; cur = nx;
      }
    }
    __builtin_amdgcn_s_setprio(1);
    #pragma unroll
    for (int ks = 0; ks < 4; ++ks) {
      acc[0][0] = MFMA(afr[0][ks], bfr[0][ks], acc[0][0], 0, 0, 0);
      acc[0][1] = MFMA(afr[0][ks], bfr[1][ks], acc[0][1], 0, 0, 0);
      acc[1][0] = MFMA(afr[1][ks], bfr[0][ks], acc[1][0], 0, 0, 0);
      acc[1][1] = MFMA(afr[1][ks], bfr[1][ks], acc[1][1], 0, 0, 0);
    }
    __builtin_amdgcn_s_setprio(0);
    asm volatile("s_waitcnt lgkmcnt(0)" ::: "memory");   // pC reads done before barrier
    if (t <= 125) asm volatile("s_waitcnt vmcnt(5)" ::: "memory");  // batch(t+1) landed
    else          asm volatile("s_waitcnt vmcnt(0)" ::: "memory");
    __builtin_amdgcn_s_barrier();
  };

  #pragma unroll 1
  for (int t3 = 0; t3 < 126; t3 += 3) {              // static ring indices, t = 0..125
    step(t3,     0, 2);
    step(t3 + 1, 1, 0);
    step(t3 + 2, 2, 1);
  }
  step(126, 0, 2);                                   // no issue (t+2 >= 128)
  step(127, 1, 0);                                   // no issue

  // epilogue: C/D layout col=lane&31, row=(r&3)+8*(r>>2)+4*h (verified)
  const int c0 = nb * 128 + wn * 64 + ml;
  float bv0 = 0.f, bv1 = 0.f;
  #pragma unroll
  for (int p = 0; p < 32; ++p) {
    bv0 += bias_p[(size_t)p * 1024 + c0];
    bv1 += bias_p[(size_t)p * 1024 + c0 + 32];
  }
  const int r0 = mt * 128 + wm * 64;
  #pragma unroll
  for (int mtt = 0; mtt < 2; ++mtt)
    #pragma unroll
    for (int r = 0; r < 16; ++r) {
      int row = r0 + mtt * 32 + (r & 3) + 8 * (r >> 2) + 4 * h;
      float* po = out + (size_t)row * 1024 + c0;
      po[0]  = acc[mtt][0][r] + bv0;
      po[32] = acc[mtt][1][r] + bv1;
    }
}

// ---- naive fallback (ws too small) — correct, slow, should never run
__global__ __launch_bounds__(256)
void cheby_naive(const float* __restrict__ x, const float* __restrict__ C,
                 float* __restrict__ out) {
  const int t = blockIdx.x, tid = threadIdx.x;
  float acc[4] = {0.f, 0.f, 0.f, 0.f};
  for (int i = 0; i < 1024; ++i) {
    float th = tanhf(x[(size_t)t * 1024 + i]);
    float T[9]; T[0] = 1.f; T[1] = th;
    #pragma unroll
    for (int d = 2; d < 9; ++d) T[d] = 2.f * th * T[d - 1] - T[d - 2];
    #pragma unroll
    for (int j = 0; j < 4; ++j) {
      const float* cp = &C[((size_t)i * 1024 + tid + j * 256) * 9];
      float s = 0.f;
      #pragma unroll
      for (int d = 0; d < 9; ++d) s += T[d] * cp[d];
      acc[j] += s;
    }
  }
  #pragma unroll
  for (int j = 0; j < 4; ++j) out[(size_t)t * 1024 + tid + j * 256] = acc[j];
}

extern "C" void kernel_launch(void* const* d_in, const int* in_sizes, int n_in,
                              void* d_out, int out_size, void* d_ws, size_t ws_size,
                              hipStream_t stream) {
  (void)in_sizes; (void)n_in; (void)out_size;
  const float* x = (const float*)d_in[0];
  const float* C = (const float*)d_in[1];
  float* out = (float*)d_out;

  const size_t b_bytes  = (size_t)8 * 128 * 8192 * 2;     // 16.78 MB
  const size_t bp_bytes = (size_t)32 * 1024 * 4;          // 128 KB
  const size_t th_bytes = (size_t)64 * 128 * 1024 * 4;    // 33.55 MB

  if (ws_size >= b_bytes + bp_bytes + th_bytes) {
    bf16*  B      = (bf16*)d_ws;
    float* bias_p = (float*)((char*)d_ws + b_bytes);
    float* th2    = (float*)((char*)d_ws + b_bytes + bp_bytes);
    cheby_prepB<<<1024, 256, 0, stream>>>(C, B, bias_p);
    cheby_prepT<<<1024, 256, 0, stream>>>(x, th2);
    cheby_gemm9<<<512, 256, 0, stream>>>(th2, B, bias_p, out);
  } else {
    cheby_naive<<<8192, 256, 0, stream>>>(x, C, out);
  }
}